// Round 2
// baseline (224.381 us; speedup 1.0000x reference)
//
#include <hip/hip_runtime.h>
#include <math.h>

// Dims: B=16, H=64, W=64, Cin=3, F=32, K=3
// Strategy: convs are VALU fp32 with weights via wave-uniform scalar loads
// (s_load) -- no LDS on the conv path at all. wave = filter-group(8 filters),
// thread = P pixels. Weights pre-transposed to [tap*32+c][32] in __device__
// global so each wave streams contiguous 32B chunks through the scalar cache.

__device__ float g_wT[9216];  // [k = tap*32+c][f = 32]

__device__ __forceinline__ float f4c(const float4 v, int cc) {
  return cc == 0 ? v.x : cc == 1 ? v.y : cc == 2 ? v.z : v.w;
}

// ---------------- transpose wsh [32][288] -> g_wT [288][32] -----------------
__global__ __launch_bounds__(256) void transpose_w(const float* __restrict__ w) {
  const int idx = threadIdx.x + blockIdx.x * 256;
  if (idx < 9216) {
    const int f = idx / 288;
    const int k = idx - f * 288;
    g_wT[k * 32 + f] = w[idx];
  }
}

// ---------------- conv0: Cin=3 -> F=32, W0 is HWIO [tap][c][f] --------------
__global__ __launch_bounds__(256) void conv0_relu(
    const float* __restrict__ in, const float* __restrict__ W0,
    const float* __restrict__ b0, float* __restrict__ out) {
  const int p = blockIdx.x * 256 + threadIdx.x;
  const int b = p >> 12;
  const int rem = p & 4095;
  const int h = rem >> 6;
  const int w = rem & 63;

  float iv[3][3][3];  // [row][col][c]
#pragma unroll
  for (int r = 0; r < 3; ++r) {
    const int hh = h - 1 + r;
    const bool vr = (unsigned)hh < 64u;
#pragma unroll
    for (int j = 0; j < 3; ++j) {
      const int col = w - 1 + j;
      const bool ok = vr && ((unsigned)col < 64u);
      const float* ip = in + (((b << 6) + hh) * 64 + col) * 3;
      iv[r][j][0] = ok ? ip[0] : 0.f;
      iv[r][j][1] = ok ? ip[1] : 0.f;
      iv[r][j][2] = ok ? ip[2] : 0.f;
    }
  }

  float acc[32];
#pragma unroll
  for (int f = 0; f < 32; ++f) acc[f] = 0.f;

#pragma unroll
  for (int dy = 0; dy < 3; ++dy) {
#pragma unroll
    for (int dx = 0; dx < 3; ++dx) {
#pragma unroll
      for (int c = 0; c < 3; ++c) {
        const float ival = iv[dy][dx][c];
        const float* wp = W0 + (((dy * 3 + dx) * 3) + c) * 32;  // uniform -> s_load
#pragma unroll
        for (int f4 = 0; f4 < 8; ++f4) {
          const float4 wv = *(const float4*)(wp + f4 * 4);
          acc[f4 * 4 + 0] += ival * wv.x;
          acc[f4 * 4 + 1] += ival * wv.y;
          acc[f4 * 4 + 2] += ival * wv.z;
          acc[f4 * 4 + 3] += ival * wv.w;
        }
      }
    }
  }

  float* op = out + p * 32;
#pragma unroll
  for (int f4 = 0; f4 < 8; ++f4) {
    const float4 bv = *(const float4*)(b0 + f4 * 4);
    float4 r;
    r.x = fmaxf(acc[f4 * 4 + 0] + bv.x, 0.f);
    r.y = fmaxf(acc[f4 * 4 + 1] + bv.y, 0.f);
    r.z = fmaxf(acc[f4 * 4 + 2] + bv.z, 0.f);
    r.w = fmaxf(acc[f4 * 4 + 3] + bv.w, 0.f);
    *(float4*)(op + f4 * 4) = r;
  }
}

// ------------- shared conv 32->32: wave = 8 filters, thread = P pixels ------
// Block = 256 threads = 4 waves = the 4 filter-groups, all covering the same
// 64*P pixels. Weight loads are wave-uniform -> scalar pipe (s_load_dwordx8).
template <int H, int W, int P>
__global__ __launch_bounds__(256) void conv_sh2(
    const float* __restrict__ in, const float* __restrict__ bsh,
    float* __restrict__ out) {
  const int lane = threadIdx.x & 63;
  const int fg = threadIdx.x >> 6;  // wave index = filter group (uniform)
  const int pxbase = blockIdx.x * (64 * P) + lane * P;
  const int b = pxbase / (H * W);
  const int rem = pxbase - b * (H * W);
  const int h = rem / W;
  const int w = rem - h * W;  // w..w+P-1 stay in this row (P | W alignment)

  constexpr int NC = P + 2;

  float acc[P][8];
#pragma unroll
  for (int p = 0; p < P; ++p)
#pragma unroll
    for (int f = 0; f < 8; ++f) acc[p][f] = 0.f;

#pragma unroll 1
  for (int c4 = 0; c4 < 8; ++c4) {
    // load input patch rows h-1..h+1, cols w-1..w+P, this channel quad
    float4 v[3][NC];
#pragma unroll
    for (int r = 0; r < 3; ++r) {
      const int hh = h - 1 + r;
      const bool vr = (unsigned)hh < (unsigned)H;
      const float* rp = in + ((b * H + hh) * W) * 32 + c4 * 4;
#pragma unroll
      for (int j = 0; j < NC; ++j) {
        const int col = w - 1 + j;
        const bool ok = vr && ((unsigned)col < (unsigned)W);
        v[r][j] = ok ? *(const float4*)(rp + col * 32) : float4{0.f, 0.f, 0.f, 0.f};
      }
    }
    // accumulate: 9 taps x 4 channels x 8 filters x P pixels
#pragma unroll
    for (int dy = 0; dy < 3; ++dy) {
#pragma unroll
      for (int dx = 0; dx < 3; ++dx) {
        const int tap = dy * 3 + dx;
#pragma unroll
        for (int cc = 0; cc < 4; ++cc) {
          // uniform address -> s_load_dwordx8 (scalar pipe, no VALU/LDS cost)
          const float* wrow = g_wT + ((tap * 32) + (c4 * 4 + cc)) * 32 + fg * 8;
          const float4 wa = *(const float4*)wrow;
          const float4 wb = *(const float4*)(wrow + 4);
#pragma unroll
          for (int p = 0; p < P; ++p) {
            const float ival = f4c(v[dy][p + dx], cc);
            acc[p][0] += ival * wa.x;
            acc[p][1] += ival * wa.y;
            acc[p][2] += ival * wa.z;
            acc[p][3] += ival * wa.w;
            acc[p][4] += ival * wb.x;
            acc[p][5] += ival * wb.y;
            acc[p][6] += ival * wb.z;
            acc[p][7] += ival * wb.w;
          }
        }
      }
    }
  }

  const float4 ba = *(const float4*)(bsh + fg * 8);
  const float4 bb = *(const float4*)(bsh + fg * 8 + 4);
#pragma unroll
  for (int p = 0; p < P; ++p) {
    float* op = out + (pxbase + p) * 32 + fg * 8;
    float4 r0, r1;
    r0.x = fmaxf(acc[p][0] + ba.x, 0.f);
    r0.y = fmaxf(acc[p][1] + ba.y, 0.f);
    r0.z = fmaxf(acc[p][2] + ba.z, 0.f);
    r0.w = fmaxf(acc[p][3] + ba.w, 0.f);
    r1.x = fmaxf(acc[p][4] + bb.x, 0.f);
    r1.y = fmaxf(acc[p][5] + bb.y, 0.f);
    r1.z = fmaxf(acc[p][6] + bb.z, 0.f);
    r1.w = fmaxf(acc[p][7] + bb.w, 0.f);
    *(float4*)op = r0;
    *(float4*)(op + 4) = r1;
  }
}

// ---------------- 2x2 maxpool stride 2, NHWC, C=32 --------------------------
template <int HO, int WO, int LGW, int LGH>
__global__ __launch_bounds__(256) void maxpool2(const float* __restrict__ in,
                                                float* __restrict__ out) {
  const int idx = blockIdx.x * 256 + threadIdx.x;  // float4 index
  const int f4 = idx & 7;
  const int r = idx >> 3;
  const int wo = r & (WO - 1);
  const int r2 = r >> LGW;
  const int ho = r2 & (HO - 1);
  const int b = r2 >> LGH;
  const int Win = WO * 2;
  const float* p00 = in + (((b * 2 * HO + 2 * ho) * Win) + 2 * wo) * 32 + f4 * 4;
  const float4 a = *(const float4*)p00;
  const float4 bb = *(const float4*)(p00 + 32);
  const float4 c = *(const float4*)(p00 + Win * 32);
  const float4 d = *(const float4*)(p00 + Win * 32 + 32);
  float4 m;
  m.x = fmaxf(fmaxf(a.x, bb.x), fmaxf(c.x, d.x));
  m.y = fmaxf(fmaxf(a.y, bb.y), fmaxf(c.y, d.y));
  m.z = fmaxf(fmaxf(a.z, bb.z), fmaxf(c.z, d.z));
  m.w = fmaxf(fmaxf(a.w, bb.w), fmaxf(c.w, d.w));
  *(float4*)(out + ((b * HO + ho) * WO + wo) * 32 + f4 * 4) = m;
}

// ---------------- dense 8192->10 + softmax, one block per batch row ---------
__global__ __launch_bounds__(256) void dense_softmax(
    const float* __restrict__ x, const float* __restrict__ Wd,
    const float* __restrict__ bd, float* __restrict__ out) {
  const int b = blockIdx.x;
  const int tid = threadIdx.x;
  const float* xb = x + b * 8192;
  float acc[10];
#pragma unroll
  for (int j = 0; j < 10; ++j) acc[j] = 0.f;
  for (int i = tid; i < 8192; i += 256) {
    const float xv = xb[i];
    const float* wr = Wd + i * 10;
#pragma unroll
    for (int j = 0; j < 10; ++j) acc[j] += xv * wr[j];
  }
  __shared__ float red[10 * 256];
#pragma unroll
  for (int j = 0; j < 10; ++j) red[j * 256 + tid] = acc[j];
  __syncthreads();
  for (int s = 128; s > 0; s >>= 1) {
    if (tid < s) {
#pragma unroll
      for (int j = 0; j < 10; ++j) red[j * 256 + tid] += red[j * 256 + tid + s];
    }
    __syncthreads();
  }
  if (tid == 0) {
    float lg[10];
    float m = -1e30f;
#pragma unroll
    for (int j = 0; j < 10; ++j) {
      lg[j] = red[j * 256] + bd[j];
      m = fmaxf(m, lg[j]);
    }
    float s = 0.f;
#pragma unroll
    for (int j = 0; j < 10; ++j) {
      lg[j] = expf(lg[j] - m);
      s += lg[j];
    }
    const float inv = 1.f / s;
#pragma unroll
    for (int j = 0; j < 10; ++j) out[b * 10 + j] = lg[j] * inv;
  }
}

extern "C" void kernel_launch(void* const* d_in, const int* in_sizes, int n_in,
                              void* d_out, int out_size, void* d_ws, size_t ws_size,
                              hipStream_t stream) {
  const float* in = (const float*)d_in[0];
  const float* W0 = (const float*)d_in[1];
  const float* b0 = (const float*)d_in[2];
  const float* wsh = (const float*)d_in[3];
  const float* bsh = (const float*)d_in[4];
  const float* Wd = (const float*)d_in[5];
  const float* bd = (const float*)d_in[6];
  float* out = (float*)d_out;

  float* A = (float*)d_ws;           // 16*64*64*32 floats (8 MB)
  float* B = A + 16 * 64 * 64 * 32;  // second 8 MB buffer

  transpose_w<<<36, 256, 0, stream>>>(wsh);
  conv0_relu<<<256, 256, 0, stream>>>(in, W0, b0, A);
  conv_sh2<64, 64, 2><<<512, 256, 0, stream>>>(A, bsh, B);
  conv_sh2<64, 64, 2><<<512, 256, 0, stream>>>(B, bsh, A);
  maxpool2<32, 32, 5, 5><<<512, 256, 0, stream>>>(A, B);  // 64x64 -> 32x32
  conv_sh2<32, 32, 1><<<256, 256, 0, stream>>>(B, bsh, A);
  conv_sh2<32, 32, 1><<<256, 256, 0, stream>>>(A, bsh, B);
  maxpool2<16, 16, 4, 4><<<128, 256, 0, stream>>>(B, A);  // 32x32 -> 16x16
  dense_softmax<<<16, 256, 0, stream>>>(A, Wd, bd, out);
}